// Round 5
// baseline (486.070 us; speedup 1.0000x reference)
//
#include <hip/hip_runtime.h>

// Swin window attention, MFMA bf16 path. fp32 global in/out.
// R10: DS-pipe diet. Phase A deleted: Phase B reads x A-frags directly from
// global (L1/L2-hot, converted in-reg), mt-outer loop => 0 LDS reads for
// A-frags (was 384 b128/block) and one fewer barrier. V tile stride-56
// (+zeroed tail; tok>=49 contributions are P=0 * finite). LDS 51,984B ->
// 3 blocks/CU with ~7KB slack regardless of reservation granule.
// P has its own region (no x alias). Barriers: 2. launch_bounds(512,4).

#define NTOK  49
#define DIMC  128
#define NBLK  4096
#define SCALE 0.17677669529663687f   // 32^-0.5
#define LOG2E 1.4426950408889634f
#define NMASK -144.26950408889634f   // -100 * LOG2E

typedef __attribute__((ext_vector_type(8))) short bf16x8;
typedef __attribute__((ext_vector_type(4))) float f32x4;

// ---- workspace layout (ushort units) ----
#define WS_QKVW 0        // 384*128 bf16 (q rows pre-scaled by SCALE*LOG2E)
#define WS_PROJW 49152   // 128*128 bf16
#define WS_BIAS  65536   // [h][mt][nt][nt][lane][reg] frag-ordered bias (x LOG2E)

// ---- LDS layout (ushort units) ----
// P : [49][128] swz  (softmax probs, both head-groups)
// Q : [49][128] swz  (Q cols h*32+d; attn-out O overlays same cols in C)
// K : [49][128] swz
// VB: V^T [128 d][56 tok] + 8 tail (zeroed); B-frag reads 8 consecutive toks
#define P_OFF  0
#define Q_OFF  6272
#define K_OFF  12544
#define VB_OFF 18816
#define VB_STRIDE 56
#define SMEM_TOT 25992   // 51,984 B -> 3 blocks/CU @ 512 thr = 24 waves/CU

// XOR swizzle for the [49][128] row-major tiles, granule 8 shorts (16B).
#define SWZ(r, c) ((r) * 128 + ((c) ^ (((r) & 7) << 3)))

__device__ __forceinline__ unsigned int pkbf2(float f0, float f1) {
    union { float f; unsigned int i; } a, b; a.f = f0; b.f = f1;
    return __builtin_amdgcn_perm(b.i + 0x8000u, a.i + 0x8000u, 0x07060302u);
}
__device__ __forceinline__ unsigned short f2b_r(float f) {
    union { float f; unsigned int i; } v; v.f = f;
    return (unsigned short)((v.i + 0x8000u) >> 16);
}
__device__ __forceinline__ float b2f_lo(unsigned int u) {
    union { unsigned int i; float f; } v; v.i = u << 16; return v.f;
}
__device__ __forceinline__ float b2f_hi(unsigned int u) {
    union { unsigned int i; float f; } v; v.i = u & 0xFFFF0000u; return v.f;
}
__device__ __forceinline__ float exp2_hw(float x) {
    float r; asm("v_exp_f32 %0, %1" : "=v"(r) : "v"(x)); return r;
}

// Swin shift-mask group id. GRID=56, WS=7, shift=3: segments [0,49)/[49,53)/[53,56)
__device__ __forceinline__ int seg3(int c) { return (c < 49) ? 0 : ((c < 53) ? 1 : 2); }

// ---------------- prep: weights fp32->bf16 (+SCALE*LOG2E fold), bias -> frag order
__global__ __launch_bounds__(256)
void prep(const float* __restrict__ qkv_w, const float* __restrict__ proj_w,
          const float* __restrict__ bias_t, const int* __restrict__ rel_idx,
          unsigned short* __restrict__ ws)
{
    int idx = blockIdx.x * 256 + threadIdx.x;
    if (idx < 8192) {
        int base = idx * 8;
        const float* sp = (base < 49152) ? (qkv_w + base) : (proj_w + (base - 49152));
        float sc = (base < 16384) ? (SCALE * LOG2E) : 1.0f;  // q rows pre-scaled
        float4 a = *(const float4*)sp;
        float4 b = *(const float4*)(sp + 4);
        uint4 u;
        u.x = pkbf2(a.x * sc, a.y * sc);
        u.y = pkbf2(a.z * sc, a.w * sc);
        u.z = pkbf2(b.x * sc, b.y * sc);
        u.w = pkbf2(b.z * sc, b.w * sc);
        *(uint4*)(ws + base) = u;
    } else {
        int i = idx - 8192;                         // [0, 16384)
        int reg = i & 3, lane = (i >> 2) & 63, nt = (i >> 8) & 3,
            mt = (i >> 10) & 3, h = (i >> 12) & 3;
        int row = mt * 16 + (lane >> 4) * 4 + reg;
        int col = nt * 16 + (lane & 15);
        float v = 0.f;
        if (row < NTOK && col < NTOK)
            v = bias_t[rel_idx[row * NTOK + col] * 4 + h] * LOG2E;
        ws[WS_BIAS + i] = f2b_r(v);
    }
}

// ---------------- main: 512 threads = 8 waves, one window ----------------
__global__ __launch_bounds__(512, 4)
void win_attn(const float* __restrict__ x,
              const float* __restrict__ qkv_b,
              const float* __restrict__ proj_b,
              const unsigned short* __restrict__ ws,
              float* __restrict__ out)
{
    __shared__ unsigned short smem[SMEM_TOT];
    const int b    = blockIdx.x;
    const int w    = b & 63;
    const int tid  = threadIdx.x;
    const int wv   = tid >> 6;     // wave id 0..7
    const int lane = tid & 63;
    const int qg   = lane >> 4;    // quad
    const int l15  = lane & 15;

    // zero the 8-short VB tail (stale-LDS NaN guard for last d-row's reads)
    if (tid == 0) {
        uint4 z = { 0u, 0u, 0u, 0u };
        *(uint4*)(smem + VB_OFF + 127 * VB_STRIDE + VB_STRIDE) = z;
    }

    // ---- Phase B: qkv GEMM; A-frags from GLOBAL x (in-reg bf16 convert) ----
    {
        const unsigned short* qw = ws + WS_QKVW;
        const int h2 = wv >> 1;                 // head this wave produces
        const int dhalf = wv & 1;
        const int dh = dhalf * 16 + l15;        // d within head 0..31
        const float* xb = x + (size_t)b * (NTOK * DIMC);
        float bias_pp[3];
        #pragma unroll
        for (int pp = 0; pp < 3; pp++) {
            int j = (pp * 8 + wv) * 16 + l15;
            bias_pp[pp] = (pp == 0) ? qkv_b[j] * (SCALE * LOG2E) : qkv_b[j];
        }
        #pragma unroll
        for (int mt = 0; mt < 4; mt++) {
            int ar = mt * 16 + l15; if (ar > 48) ar = 48;
            const float* xr = xb + ar * DIMC;
            bf16x8 af[4];
            #pragma unroll
            for (int ks_ = 0; ks_ < 4; ks_++) {
                float4 lo = *(const float4*)(xr + ks_ * 32 + qg * 8);
                float4 hi = *(const float4*)(xr + ks_ * 32 + qg * 8 + 4);
                union { uint4 u; bf16x8 v; } cv;
                cv.u.x = pkbf2(lo.x, lo.y); cv.u.y = pkbf2(lo.z, lo.w);
                cv.u.z = pkbf2(hi.x, hi.y); cv.u.w = pkbf2(hi.z, hi.w);
                af[ks_] = cv.v;
            }
            #pragma unroll
            for (int pp = 0; pp < 3; pp++) {    // 0=q 1=k 2=v
                const int j = (pp * 8 + wv) * 16 + l15;
                f32x4 acc = { bias_pp[pp], bias_pp[pp], bias_pp[pp], bias_pp[pp] };
                #pragma unroll
                for (int ks_ = 0; ks_ < 4; ks_++) {
                    bf16x8 bfr = *(const bf16x8*)(qw + j * DIMC + ks_ * 32 + qg * 8);
                    acc = __builtin_amdgcn_mfma_f32_16x16x32_bf16(af[ks_], bfr, acc, 0, 0, 0);
                }
                if (pp == 0) {
                    #pragma unroll
                    for (int r = 0; r < 4; r++) {
                        int row = mt * 16 + qg * 4 + r;
                        if (row < NTOK)
                            smem[Q_OFF + SWZ(row, h2 * 32 + dh)] = f2b_r(acc[r]);
                    }
                } else if (pp == 1) {
                    #pragma unroll
                    for (int r = 0; r < 4; r++) {
                        int row = mt * 16 + qg * 4 + r;
                        if (row < NTOK)
                            smem[K_OFF + SWZ(row, h2 * 32 + dh)] = f2b_r(acc[r]);
                    }
                } else {
                    // V^T[d][tok] stride 56; guard keeps writes inside the row
                    int tokbase = mt * 16 + qg * 4;
                    if (tokbase <= 52) {
                        uint2 u; u.x = pkbf2(acc[0], acc[1]); u.y = pkbf2(acc[2], acc[3]);
                        *(uint2*)(smem + VB_OFF + (h2 * 32 + dh) * VB_STRIDE + tokbase) = u;
                    }
                }
            }
        }
    }
    __syncthreads();

    // ---- Phase C: attention; wave = (M-strip, head-pair) ----
    const int g  = wv >> 2;        // head group: heads {2g, 2g+1}
    const int st = wv & 3;         // M-strip
    const int r0 = st * 16;
    const int wy = w >> 3, wx = w & 7;
    int grow[4];
    #pragma unroll
    for (int r = 0; r < 4; r++) {
        int t = r0 + qg * 4 + r;
        int ty = (t * 9363) >> 16, tx = t - ty * 7;
        grow[r] = seg3(wy * 7 + ty) * 3 + seg3(wx * 7 + tx);
    }
    int arq = r0 + l15; if (arq > 48) arq = 48;

    #pragma unroll
    for (int hh = 0; hh < 2; hh++) {
        const int h = 2 * g + hh;
        // aq read before this wave's O-write for hh lands in cols h*32..
        // (hh=0 O-write hits cols (2g)*32; hh=1 aq read is cols (2g+1)*32)
        const bf16x8 aq = *(const bf16x8*)(smem + Q_OFF + SWZ(arq, h * 32 + qg * 8));
        float sv[4][4];
        #pragma unroll
        for (int nt = 0; nt < 4; nt++) {
            int krow = nt * 16 + l15; if (krow > 48) krow = 48;
            bf16x8 bk = *(const bf16x8*)(smem + K_OFF + SWZ(krow, h * 32 + qg * 8));
            f32x4 z = { 0.f, 0.f, 0.f, 0.f };
            f32x4 c = __builtin_amdgcn_mfma_f32_16x16x32_bf16(aq, bk, z, 0, 0, 0);
            uint2 bb = *(const uint2*)(ws + WS_BIAS + (((h * 4 + st) * 4 + nt) * 64 + lane) * 4);
            int t = nt * 16 + l15;
            int ty = (t * 9363) >> 16, tx = t - ty * 7;
            int gcol = seg3(wy * 7 + ty) * 3 + seg3(wx * 7 + tx);
            bool vc = t < NTOK;
            float bv[4] = { b2f_lo(bb.x), b2f_hi(bb.x), b2f_lo(bb.y), b2f_hi(bb.y) };
            #pragma unroll
            for (int r = 0; r < 4; r++) {
                float v = c[r] + bv[r] + ((grow[r] == gcol) ? 0.f : NMASK);
                sv[nt][r] = vc ? v : -1e30f;
            }
        }
        float inv[4];
        #pragma unroll
        for (int r = 0; r < 4; r++) {
            float mx = fmaxf(fmaxf(sv[0][r], sv[1][r]), fmaxf(sv[2][r], sv[3][r]));
            mx = fmaxf(mx, __shfl_xor(mx, 1));
            mx = fmaxf(mx, __shfl_xor(mx, 2));
            mx = fmaxf(mx, __shfl_xor(mx, 4));
            mx = fmaxf(mx, __shfl_xor(mx, 8));
            float sum = 0.f;
            #pragma unroll
            for (int nt = 0; nt < 4; nt++) {
                float e = exp2_hw(sv[nt][r] - mx);   // logits pre-scaled by LOG2E
                sv[nt][r] = e; sum += e;
            }
            sum += __shfl_xor(sum, 1);
            sum += __shfl_xor(sum, 2);
            sum += __shfl_xor(sum, 4);
            sum += __shfl_xor(sum, 8);
            inv[r] = __builtin_amdgcn_rcpf(sum);     // deferred normalization
        }
        // P -> own region (own strip rows; g groups in disjoint cols)
        #pragma unroll
        for (int nt = 0; nt < 4; nt++)
            #pragma unroll
            for (int r = 0; r < 4; r++) {
                int row = r0 + qg * 4 + r;
                if (row < NTOK)
                    smem[P_OFF + SWZ(row, g * 64 + nt * 16 + l15)] = f2b_r(sv[nt][r]);
            }
        // PV: A = P strip, B = V^T rows (8 consecutive toks per lane)
        f32x4 accO[2] = { { 0.f, 0.f, 0.f, 0.f }, { 0.f, 0.f, 0.f, 0.f } };
        #pragma unroll
        for (int ks2 = 0; ks2 < 2; ks2++) {
            bf16x8 ap = *(const bf16x8*)(smem + P_OFF + SWZ(arq, g * 64 + ks2 * 32 + qg * 8));
            #pragma unroll
            for (int nt2 = 0; nt2 < 2; nt2++) {
                bf16x8 bvv = *(const bf16x8*)(smem + VB_OFF
                              + (h * 32 + nt2 * 16 + l15) * VB_STRIDE + ks2 * 32 + qg * 8);
                accO[nt2] = __builtin_amdgcn_mfma_f32_16x16x32_bf16(ap, bvv, accO[nt2], 0, 0, 0);
            }
        }
        // O -> Q cols h*32.. (clobbers only own-wave's already-read aq)
        #pragma unroll
        for (int nt2 = 0; nt2 < 2; nt2++)
            #pragma unroll
            for (int r = 0; r < 4; r++) {
                int row = r0 + qg * 4 + r;
                if (row < NTOK)
                    smem[Q_OFF + SWZ(row, h * 32 + nt2 * 16 + l15)] =
                        f2b_r(accO[nt2][r] * inv[r]);
            }
    }
    __syncthreads();

    // ---- Phase D: proj; wave = (M-strip, col-half) ----
    {
        const int mt = wv & 3, jh = wv >> 2;
        int ar = mt * 16 + l15; if (ar > 48) ar = 48;
        bf16x8 ad[4];
        #pragma unroll
        for (int ks_ = 0; ks_ < 4; ks_++)   // k-block = head block of attn-out
            ad[ks_] = *(const bf16x8*)(smem + Q_OFF + SWZ(ar, ks_ * 32 + qg * 8));
        const unsigned short* pw = ws + WS_PROJW;
        float* ob = out + (size_t)b * (NTOK * DIMC);
        #pragma unroll
        for (int jt2 = 0; jt2 < 4; jt2++) {
            const int j = jh * 64 + jt2 * 16 + l15;
            bf16x8 bfr[4];
            #pragma unroll
            for (int ks_ = 0; ks_ < 4; ks_++)
                bfr[ks_] = *(const bf16x8*)(pw + j * DIMC + ks_ * 32 + qg * 8);
            const float pb = proj_b[j];
            f32x4 acc = { pb, pb, pb, pb };
            #pragma unroll
            for (int ks_ = 0; ks_ < 4; ks_++)
                acc = __builtin_amdgcn_mfma_f32_16x16x32_bf16(ad[ks_], bfr[ks_], acc, 0, 0, 0);
            #pragma unroll
            for (int r = 0; r < 4; r++) {
                int row = mt * 16 + qg * 4 + r;
                if (row < NTOK) ob[row * DIMC + j] = acc[r];
            }
        }
    }
}

extern "C" void kernel_launch(void* const* d_in, const int* in_sizes, int n_in,
                              void* d_out, int out_size, void* d_ws, size_t ws_size,
                              hipStream_t stream) {
    const float* x      = (const float*)d_in[0];
    // d_in[1] = mask (recomputed arithmetically)
    const float* qkv_w  = (const float*)d_in[2];
    const float* qkv_b  = (const float*)d_in[3];
    const float* proj_w = (const float*)d_in[4];
    const float* proj_b = (const float*)d_in[5];
    const float* bias_t = (const float*)d_in[6];
    const int*   relidx = (const int*)d_in[7];
    float*       outp   = (float*)d_out;
    unsigned short* ws  = (unsigned short*)d_ws;

    prep<<<96, 256, 0, stream>>>(qkv_w, proj_w, bias_t, relidx, ws);
    win_attn<<<NBLK, 512, 0, stream>>>(x, qkv_b, proj_b, ws, outp);
}

// Round 6
// 308.152 us; speedup vs baseline: 1.5774x; 1.5774x over previous
//
#include <hip/hip_runtime.h>

// Swin window attention, MFMA bf16 path. fp32 global in/out.
// R11: LDS 39,440B via 3-region time-share => target 3-4 blocks/CU.
//  QPO [49][128]: Q (B) -> per-wave P scratch (C; wave (g,st) owns rows
//    r0..+15 x cols g*64..+63 after aq pre-read) -> O odd heads.
//  KX  [49][128]: x stage (A) -> K (B, deferred in 8 VGPR, written after
//    barrier) -> O even heads (C, after mid-C barrier; those cols only
//    read in hh=0).
//  VB  [128][56]+8: V^T d-major (written directly in B).
// Phase D picks O region by head parity. x staged via LDS (R10's global-x
// refuted: scattered rows thrash L1). Barriers: 5. launch_bounds(512,4).

#define NTOK  49
#define DIMC  128
#define NBLK  4096
#define SCALE 0.17677669529663687f   // 32^-0.5
#define LOG2E 1.4426950408889634f
#define NMASK -144.26950408889634f   // -100 * LOG2E

typedef __attribute__((ext_vector_type(8))) short bf16x8;
typedef __attribute__((ext_vector_type(4))) float f32x4;

// ---- workspace layout (ushort units) ----
#define WS_QKVW 0        // 384*128 bf16 (q rows pre-scaled by SCALE*LOG2E)
#define WS_PROJW 49152   // 128*128 bf16
#define WS_BIAS  65536   // frag-ordered bias (x LOG2E)

// ---- LDS layout (ushort units) ----
#define QPO_OFF 0        // [49][128] swz
#define KX_OFF  6272     // [49][128] swz
#define VB_OFF  12544    // V^T [128 d][56 tok] + 8 tail
#define VB_STRIDE 56
#define SMEM_TOT 19720   // 39,440 B

// XOR swizzle for [49][128] row-major tiles, granule 8 shorts (16B).
#define SWZ(r, c) ((r) * 128 + ((c) ^ (((r) & 7) << 3)))

__device__ __forceinline__ unsigned int pkbf2(float f0, float f1) {
    union { float f; unsigned int i; } a, b; a.f = f0; b.f = f1;
    return __builtin_amdgcn_perm(b.i + 0x8000u, a.i + 0x8000u, 0x07060302u);
}
__device__ __forceinline__ unsigned short f2b_r(float f) {
    union { float f; unsigned int i; } v; v.f = f;
    return (unsigned short)((v.i + 0x8000u) >> 16);
}
__device__ __forceinline__ float b2f_lo(unsigned int u) {
    union { unsigned int i; float f; } v; v.i = u << 16; return v.f;
}
__device__ __forceinline__ float b2f_hi(unsigned int u) {
    union { unsigned int i; float f; } v; v.i = u & 0xFFFF0000u; return v.f;
}
__device__ __forceinline__ float exp2_hw(float x) {
    float r; asm("v_exp_f32 %0, %1" : "=v"(r) : "v"(x)); return r;
}

// Swin shift-mask group id. GRID=56, WS=7, shift=3: segments [0,49)/[49,53)/[53,56)
__device__ __forceinline__ int seg3(int c) { return (c < 49) ? 0 : ((c < 53) ? 1 : 2); }

// ---------------- prep: weights fp32->bf16 (+SCALE*LOG2E fold), bias -> frag order
__global__ __launch_bounds__(256)
void prep(const float* __restrict__ qkv_w, const float* __restrict__ proj_w,
          const float* __restrict__ bias_t, const int* __restrict__ rel_idx,
          unsigned short* __restrict__ ws)
{
    int idx = blockIdx.x * 256 + threadIdx.x;
    if (idx < 8192) {
        int base = idx * 8;
        const float* sp = (base < 49152) ? (qkv_w + base) : (proj_w + (base - 49152));
        float sc = (base < 16384) ? (SCALE * LOG2E) : 1.0f;  // q rows pre-scaled
        float4 a = *(const float4*)sp;
        float4 b = *(const float4*)(sp + 4);
        uint4 u;
        u.x = pkbf2(a.x * sc, a.y * sc);
        u.y = pkbf2(a.z * sc, a.w * sc);
        u.z = pkbf2(b.x * sc, b.y * sc);
        u.w = pkbf2(b.z * sc, b.w * sc);
        *(uint4*)(ws + base) = u;
    } else {
        int i = idx - 8192;                         // [0, 16384)
        int reg = i & 3, lane = (i >> 2) & 63, nt = (i >> 8) & 3,
            mt = (i >> 10) & 3, h = (i >> 12) & 3;
        int row = mt * 16 + (lane >> 4) * 4 + reg;
        int col = nt * 16 + (lane & 15);
        float v = 0.f;
        if (row < NTOK && col < NTOK)
            v = bias_t[rel_idx[row * NTOK + col] * 4 + h] * LOG2E;
        ws[WS_BIAS + i] = f2b_r(v);
    }
}

// ---------------- main: 512 threads = 8 waves, one window ----------------
__global__ __launch_bounds__(512, 4)
void win_attn(const float* __restrict__ x,
              const float* __restrict__ qkv_b,
              const float* __restrict__ proj_b,
              const unsigned short* __restrict__ ws,
              float* __restrict__ out)
{
    __shared__ unsigned short smem[SMEM_TOT];
    const int b    = blockIdx.x;
    const int w    = b & 63;
    const int tid  = threadIdx.x;
    const int wv   = tid >> 6;     // wave id 0..7
    const int lane = tid & 63;
    const int qg   = lane >> 4;    // quad
    const int l15  = lane & 15;

    // zero the 8-short VB tail (stale-LDS NaN guard: P=0 x NaN = NaN in MFMA)
    if (tid == 0) {
        uint4 z = { 0u, 0u, 0u, 0u };
        *(uint4*)(smem + VB_OFF + 127 * VB_STRIDE + VB_STRIDE) = z;
    }

    // ---- Phase A: stage x -> bf16 LDS [49][128] swz in KX ----
    {
        const float4* xg = (const float4*)(x + (size_t)b * (NTOK * DIMC));
        #pragma unroll
        for (int it = 0; it < 4; it++) {
            int i = tid + it * 512;
            if (i < NTOK * DIMC / 4) {
                float4 v = xg[i];
                int row = i >> 5, col = (i & 31) * 4;
                uint2 u; u.x = pkbf2(v.x, v.y); u.y = pkbf2(v.z, v.w);
                *(uint2*)(smem + KX_OFF + SWZ(row, col)) = u;
            }
        }
    }
    __syncthreads();

    // ---- Phase B: qkv GEMM; Q/V written now, K held in 8 VGPR ----
    uint2 kreg[4];
    {
        const unsigned short* qw = ws + WS_QKVW;
        const int h2 = wv >> 1;                 // head this wave produces
        const int dhalf = wv & 1;
        const int dh = dhalf * 16 + l15;        // d within head 0..31
        float bias_pp[3];
        #pragma unroll
        for (int pp = 0; pp < 3; pp++) {
            int j = (pp * 8 + wv) * 16 + l15;
            bias_pp[pp] = (pp == 0) ? qkv_b[j] * (SCALE * LOG2E) : qkv_b[j];
        }
        #pragma unroll
        for (int mt = 0; mt < 4; mt++) {
            int ar = mt * 16 + l15; if (ar > 48) ar = 48;
            bf16x8 af[4];
            #pragma unroll
            for (int ks_ = 0; ks_ < 4; ks_++)
                af[ks_] = *(const bf16x8*)(smem + KX_OFF + SWZ(ar, ks_ * 32 + qg * 8));
            #pragma unroll
            for (int pp = 0; pp < 3; pp++) {    // 0=q 1=k 2=v
                const int j = (pp * 8 + wv) * 16 + l15;
                f32x4 acc = { bias_pp[pp], bias_pp[pp], bias_pp[pp], bias_pp[pp] };
                #pragma unroll
                for (int ks_ = 0; ks_ < 4; ks_++) {
                    bf16x8 bfr = *(const bf16x8*)(qw + j * DIMC + ks_ * 32 + qg * 8);
                    acc = __builtin_amdgcn_mfma_f32_16x16x32_bf16(af[ks_], bfr, acc, 0, 0, 0);
                }
                if (pp == 0) {
                    #pragma unroll
                    for (int r = 0; r < 4; r++) {
                        int row = mt * 16 + qg * 4 + r;
                        if (row < NTOK)
                            smem[QPO_OFF + SWZ(row, h2 * 32 + dh)] = f2b_r(acc[r]);
                    }
                } else if (pp == 1) {
                    kreg[mt].x = pkbf2(acc[0], acc[1]);   // defer: x still live in KX
                    kreg[mt].y = pkbf2(acc[2], acc[3]);
                } else {
                    // V^T[d][tok] stride 56; guard keeps writes inside the row
                    int tokbase = mt * 16 + qg * 4;
                    if (tokbase <= 52) {
                        uint2 u; u.x = pkbf2(acc[0], acc[1]); u.y = pkbf2(acc[2], acc[3]);
                        *(uint2*)(smem + VB_OFF + (h2 * 32 + dh) * VB_STRIDE + tokbase) = u;
                    }
                }
            }
        }
    }
    __syncthreads();   // all x reads complete
    // K regs -> KX (x dead)
    {
        const int h2 = wv >> 1;
        const int dh = (wv & 1) * 16 + l15;
        #pragma unroll
        for (int mt = 0; mt < 4; mt++) {
            unsigned short kv0 = (unsigned short)(kreg[mt].x & 0xFFFFu);
            unsigned short kv1 = (unsigned short)(kreg[mt].x >> 16);
            unsigned short kv2 = (unsigned short)(kreg[mt].y & 0xFFFFu);
            unsigned short kv3 = (unsigned short)(kreg[mt].y >> 16);
            int row = mt * 16 + qg * 4;
            if (row     < NTOK) smem[KX_OFF + SWZ(row,     h2 * 32 + dh)] = kv0;
            if (row + 1 < NTOK) smem[KX_OFF + SWZ(row + 1, h2 * 32 + dh)] = kv1;
            if (row + 2 < NTOK) smem[KX_OFF + SWZ(row + 2, h2 * 32 + dh)] = kv2;
            if (row + 3 < NTOK) smem[KX_OFF + SWZ(row + 3, h2 * 32 + dh)] = kv3;
        }
    }
    __syncthreads();

    // ---- Phase C: attention; wave = (M-strip, head-pair) ----
    const int g  = wv >> 2;        // head group: heads {2g, 2g+1}
    const int st = wv & 3;         // M-strip
    const int r0 = st * 16;
    const int wy = w >> 3, wx = w & 7;
    int grow[4];
    #pragma unroll
    for (int r = 0; r < 4; r++) {
        int t = r0 + qg * 4 + r;
        int ty = (t * 9363) >> 16, tx = t - ty * 7;
        grow[r] = seg3(wy * 7 + ty) * 3 + seg3(wx * 7 + tx);
    }
    int arq = r0 + l15; if (arq > 48) arq = 48;

    // pre-read both heads' Q before P overwrites these cells
    const bf16x8 aq0 = *(const bf16x8*)(smem + QPO_OFF + SWZ(arq, (2 * g) * 32 + qg * 8));
    const bf16x8 aq1 = *(const bf16x8*)(smem + QPO_OFF + SWZ(arq, (2 * g + 1) * 32 + qg * 8));

    #pragma unroll
    for (int hh = 0; hh < 2; hh++) {
        const int h = 2 * g + hh;
        const bf16x8 aq = hh ? aq1 : aq0;
        float sv[4][4];
        #pragma unroll
        for (int nt = 0; nt < 4; nt++) {
            int krow = nt * 16 + l15; if (krow > 48) krow = 48;
            bf16x8 bk = *(const bf16x8*)(smem + KX_OFF + SWZ(krow, h * 32 + qg * 8));
            f32x4 z = { 0.f, 0.f, 0.f, 0.f };
            f32x4 c = __builtin_amdgcn_mfma_f32_16x16x32_bf16(aq, bk, z, 0, 0, 0);
            uint2 bb = *(const uint2*)(ws + WS_BIAS + (((h * 4 + st) * 4 + nt) * 64 + lane) * 4);
            int t = nt * 16 + l15;
            int ty = (t * 9363) >> 16, tx = t - ty * 7;
            int gcol = seg3(wy * 7 + ty) * 3 + seg3(wx * 7 + tx);
            bool vc = t < NTOK;
            float bv[4] = { b2f_lo(bb.x), b2f_hi(bb.x), b2f_lo(bb.y), b2f_hi(bb.y) };
            #pragma unroll
            for (int r = 0; r < 4; r++) {
                float v = c[r] + bv[r] + ((grow[r] == gcol) ? 0.f : NMASK);
                sv[nt][r] = vc ? v : -1e30f;
            }
        }
        float inv[4];
        #pragma unroll
        for (int r = 0; r < 4; r++) {
            float mx = fmaxf(fmaxf(sv[0][r], sv[1][r]), fmaxf(sv[2][r], sv[3][r]));
            mx = fmaxf(mx, __shfl_xor(mx, 1));
            mx = fmaxf(mx, __shfl_xor(mx, 2));
            mx = fmaxf(mx, __shfl_xor(mx, 4));
            mx = fmaxf(mx, __shfl_xor(mx, 8));
            float sum = 0.f;
            #pragma unroll
            for (int nt = 0; nt < 4; nt++) {
                float e = exp2_hw(sv[nt][r] - mx);   // logits pre-scaled by LOG2E
                sv[nt][r] = e; sum += e;
            }
            sum += __shfl_xor(sum, 1);
            sum += __shfl_xor(sum, 2);
            sum += __shfl_xor(sum, 4);
            sum += __shfl_xor(sum, 8);
            inv[r] = __builtin_amdgcn_rcpf(sum);     // deferred normalization
        }
        // P -> own QPO cells (rows r0..+15 x cols g*64..+63, aq consumed)
        #pragma unroll
        for (int nt = 0; nt < 4; nt++)
            #pragma unroll
            for (int r = 0; r < 4; r++) {
                int row = r0 + qg * 4 + r;
                if (row < NTOK)
                    smem[QPO_OFF + SWZ(row, g * 64 + nt * 16 + l15)] = f2b_r(sv[nt][r]);
            }
        // PV: A = P (own cells), B = V^T rows
        f32x4 accO[2] = { { 0.f, 0.f, 0.f, 0.f }, { 0.f, 0.f, 0.f, 0.f } };
        #pragma unroll
        for (int ks2 = 0; ks2 < 2; ks2++) {
            bf16x8 ap = *(const bf16x8*)(smem + QPO_OFF + SWZ(arq, g * 64 + ks2 * 32 + qg * 8));
            #pragma unroll
            for (int nt2 = 0; nt2 < 2; nt2++) {
                bf16x8 bvv = *(const bf16x8*)(smem + VB_OFF
                              + (h * 32 + nt2 * 16 + l15) * VB_STRIDE + ks2 * 32 + qg * 8);
                accO[nt2] = __builtin_amdgcn_mfma_f32_16x16x32_bf16(ap, bvv, accO[nt2], 0, 0, 0);
            }
        }
        if (hh == 0) {
            // all waves' hh=0 K-reads (cols g*64..+31) are done after this
            __syncthreads();
            // O(even head) -> KX cols g*64..+31 (K there is dead now)
            #pragma unroll
            for (int nt2 = 0; nt2 < 2; nt2++)
                #pragma unroll
                for (int r = 0; r < 4; r++) {
                    int row = r0 + qg * 4 + r;
                    if (row < NTOK)
                        smem[KX_OFF + SWZ(row, g * 64 + nt2 * 16 + l15)] =
                            f2b_r(accO[nt2][r] * inv[r]);
                }
        } else {
            // O(odd head) -> QPO cols g*64..+31 (over dead P)
            #pragma unroll
            for (int nt2 = 0; nt2 < 2; nt2++)
                #pragma unroll
                for (int r = 0; r < 4; r++) {
                    int row = r0 + qg * 4 + r;
                    if (row < NTOK)
                        smem[QPO_OFF + SWZ(row, g * 64 + nt2 * 16 + l15)] =
                            f2b_r(accO[nt2][r] * inv[r]);
                }
        }
    }
    __syncthreads();

    // ---- Phase D: proj; wave = (M-strip, col-half) ----
    // O layout: head h at cols (h>>1)*64 .. +31 of (h&1 ? QPO : KX)
    {
        const int mt = wv & 3, jh = wv >> 2;
        int ar = mt * 16 + l15; if (ar > 48) ar = 48;
        bf16x8 ad[4];
        #pragma unroll
        for (int ks_ = 0; ks_ < 4; ks_++) {
            int base = (ks_ >> 1) * 64 + qg * 8;
            ad[ks_] = (ks_ & 1)
                ? *(const bf16x8*)(smem + QPO_OFF + SWZ(ar, base))
                : *(const bf16x8*)(smem + KX_OFF  + SWZ(ar, base));
        }
        const unsigned short* pw = ws + WS_PROJW;
        float* ob = out + (size_t)b * (NTOK * DIMC);
        #pragma unroll
        for (int jt2 = 0; jt2 < 4; jt2++) {
            const int j = jh * 64 + jt2 * 16 + l15;
            bf16x8 bfr[4];
            #pragma unroll
            for (int ks_ = 0; ks_ < 4; ks_++)
                bfr[ks_] = *(const bf16x8*)(pw + j * DIMC + ks_ * 32 + qg * 8);
            const float pb = proj_b[j];
            f32x4 acc = { pb, pb, pb, pb };
            #pragma unroll
            for (int ks_ = 0; ks_ < 4; ks_++)
                acc = __builtin_amdgcn_mfma_f32_16x16x32_bf16(ad[ks_], bfr[ks_], acc, 0, 0, 0);
            #pragma unroll
            for (int r = 0; r < 4; r++) {
                int row = mt * 16 + qg * 4 + r;
                if (row < NTOK) ob[row * DIMC + j] = acc[r];
            }
        }
    }
}

extern "C" void kernel_launch(void* const* d_in, const int* in_sizes, int n_in,
                              void* d_out, int out_size, void* d_ws, size_t ws_size,
                              hipStream_t stream) {
    const float* x      = (const float*)d_in[0];
    // d_in[1] = mask (recomputed arithmetically)
    const float* qkv_w  = (const float*)d_in[2];
    const float* qkv_b  = (const float*)d_in[3];
    const float* proj_w = (const float*)d_in[4];
    const float* proj_b = (const float*)d_in[5];
    const float* bias_t = (const float*)d_in[6];
    const int*   relidx = (const int*)d_in[7];
    float*       outp   = (float*)d_out;
    unsigned short* ws  = (unsigned short*)d_ws;

    prep<<<96, 256, 0, stream>>>(qkv_w, proj_w, bias_t, relidx, ws);
    win_attn<<<NBLK, 512, 0, stream>>>(x, qkv_b, proj_b, ws, outp);
}